// Round 19
// baseline (70.178 us; speedup 1.0000x reference)
//
#include <hip/hip_runtime.h>
#include <hip/hip_bf16.h>

// N=4096, PAIR=2, M=64, D=128, O=128, R=2, MAX_DEG=32
// h = relu(x @ (d*Wsum + W0) + (d*bsum + b0));  out[n] = h0 @ h1^T
//
// Round 18: R17 (512-thread, 2-barrier, DMA-W, 69.4us) with ONE change:
// x loads issued FIRST (they depend only on blockIdx), before the
// deg-dependent W/bias DMAs. Previously every block's memory stream sat
// behind the deg[n] scalar-load latency; now the 64 KB x burst starts at
// block cycle ~0 and deg/W staging overlaps it.

typedef __attribute__((ext_vector_type(8))) short bf16x8;
typedef __attribute__((ext_vector_type(4))) float f32x4;

#define RAW_BARRIER() do {                                   \
    asm volatile("s_waitcnt lgkmcnt(0)" ::: "memory");       \
    __builtin_amdgcn_s_barrier();                            \
    __builtin_amdgcn_sched_barrier(0);                       \
} while (0)

__device__ __forceinline__ unsigned int pkbf(float a, float b) {
    union { __hip_bfloat162 h; unsigned int u; } v;
    v.h = __float22bfloat162_rn(float2{a, b});
    return v.u;
}

__global__ __launch_bounds__(256) void build_weights(
    const float* __restrict__ W_r,  // [2,128,128]
    const float* __restrict__ b_r,  // [2,128]
    const float* __restrict__ W0,   // [128,128]
    const float* __restrict__ b0,   // [128]
    unsigned short* __restrict__ wfrag,  // [32][8*4*64*8]  (32 KB per deg)
    float* __restrict__ call)            // [32*128]
{
    const int t = blockIdx.x * blockDim.x + threadIdx.x;   // 0..65535
    const int d = t >> 11;            // 0..31
    const int r = t & 2047;
    const int k = r >> 4;             // 0..127
    const int o0 = (r & 15) * 8;      // 8-aligned -> ct constant over the 8
    const f32x4* wr0 = (const f32x4*)(W_r + k * 128 + o0);
    const f32x4* wr1 = (const f32x4*)(W_r + 128 * 128 + k * 128 + o0);
    const f32x4* w0p = (const f32x4*)(W0 + k * 128 + o0);
    float w[8];
#pragma unroll
    for (int half = 0; half < 2; ++half) {
        f32x4 a = wr0[half], b = wr1[half], c = w0p[half];
#pragma unroll
        for (int i = 0; i < 4; ++i)
            w[half * 4 + i] = (float)d * (a[i] + b[i]) + c[i];
    }
    const int ct = o0 >> 4;
    const int ks = k >> 5;
    const int lhi = (k >> 3) & 3;
    const int j = k & 7;
    unsigned short* base = wfrag +
        ((((size_t)(d * 8 + ct) * 4 + ks) * 64 + lhi * 16 + (o0 & 15))) * 8 + j;
#pragma unroll
    for (int i = 0; i < 8; ++i) {
        union { float f; unsigned u; } v; v.f = w[i];
        unsigned rr = (v.u + 0x7fffu + ((v.u >> 16) & 1u)) >> 16;
        base[i * 8] = (unsigned short)rr;
    }
    if (t < 32 * 128) {
        int dd = t >> 7, oo = t & 127;
        call[t] = (float)dd * (b_r[oo] + b_r[128 + oo]) + b0[oo];
    }
}

__global__ __launch_bounds__(512) void edge_kernel(
    const float* __restrict__ x,    // [N,2,64,128] f32
    const int* __restrict__ deg,    // [N]
    const unsigned short* __restrict__ wfrag,
    const float* __restrict__ call,
    float* __restrict__ out)        // [N,64,64] f32
{
    // [0,32K): W frags | [32K,64K): h | [64K,+512): bias
    __shared__ char ldsb[66048];

    const int n = blockIdx.x;
    const int tid = threadIdx.x;
    const int wave = tid >> 6;      // 0..7
    const int lane = tid & 63;
    const int l15 = lane & 15;
    const int lhi = lane >> 4;      // 0..3

    // ---- x FIRST: wave owns rows wave*16..+15; all 8 loads at cycle ~0 ----
    const float* xn = x + (size_t)n * (2 * 64 * 128);
    const float* r0p = xn + (size_t)(wave * 16 + l15) * 128 + lhi * 8;
    f32x4 xraw[4][2];
#pragma unroll
    for (int ks = 0; ks < 4; ++ks) {
        const f32x4* p0 = (const f32x4*)(r0p + ks * 32);
        xraw[ks][0] = p0[0];
        xraw[ks][1] = p0[1];
    }

    // ---- deg + W/bias staging (overlaps the x burst) ----
    const int d = deg[n];
    const char* wsrc = (const char*)(wfrag + (size_t)d * (8 * 4 * 64 * 8));
#pragma unroll
    for (int i = 0; i < 4; ++i) {
        __builtin_amdgcn_global_load_lds(
            (const __attribute__((address_space(1))) unsigned int*)(wsrc + (size_t)i * 8192 + (size_t)tid * 16),
            (__attribute__((address_space(3))) unsigned int*)(ldsb + i * 8192 + wave * 1024),
            16, 0, 0);
    }
    if (tid < 32) {
        __builtin_amdgcn_global_load_lds(
            (const __attribute__((address_space(1))) unsigned int*)(call + d * 128 + tid * 4),
            (__attribute__((address_space(3))) unsigned int*)(ldsb + 65536),
            16, 0, 0);
    }

    // ---- convert own rows ----
    bf16x8 afrag[4];
#pragma unroll
    for (int ks = 0; ks < 4; ++ks) {
        f32x4 a0 = xraw[ks][0];
        f32x4 a1 = xraw[ks][1];
        union { bf16x8 vv; unsigned int uu[4]; } f;
        f.uu[0] = pkbf(a0.x, a0.y);
        f.uu[1] = pkbf(a0.z, a0.w);
        f.uu[2] = pkbf(a1.x, a1.y);
        f.uu[3] = pkbf(a1.z, a1.w);
        afrag[ks] = f.vv;
    }

    __syncthreads();   // drains staging DMAs; W + bias visible  [barrier 1/2]

    // ---- GEMM1 (swapped): D[o][m] = mfma(Wfrag, Xfrag); NO barriers ----
    // h layout: byte = 32768 + ct*4096 + m*32 + slot*16 + (lhi&1)*8,
    //           slot = (lhi>>1) ^ ((m>>2)&1)
#pragma unroll
    for (int ct = 0; ct < 8; ++ct) {
        bf16x8 bfrag[4];
#pragma unroll
        for (int ks = 0; ks < 4; ++ks)
            bfrag[ks] = *(const bf16x8*)(ldsb + ct * 4096 + ks * 1024 + lane * 16);
        f32x4 acc = {0.f, 0.f, 0.f, 0.f};
#pragma unroll
        for (int ks = 0; ks < 4; ++ks)
            acc = __builtin_amdgcn_mfma_f32_16x16x32_bf16(bfrag[ks], afrag[ks], acc, 0, 0, 0);
        const f32x4 cc4 = *(const f32x4*)(ldsb + 65536 + ct * 64 + lhi * 16);
        const int m = wave * 16 + l15;
        const int slot = ((lhi >> 1) ^ ((m >> 2) & 1));
        float h0v = fmaxf(acc[0] + cc4.x, 0.f);
        float h1v = fmaxf(acc[1] + cc4.y, 0.f);
        float h2v = fmaxf(acc[2] + cc4.z, 0.f);
        float h3v = fmaxf(acc[3] + cc4.w, 0.f);
        union { unsigned int u[2]; unsigned long long ull; } pk;
        pk.u[0] = pkbf(h0v, h1v);
        pk.u[1] = pkbf(h2v, h3v);
        *(unsigned long long*)(ldsb + 32768 + ct * 4096 + m * 32 + slot * 16 + (lhi & 1) * 8) = pk.ull;
    }
    RAW_BARRIER();   // h fully visible  [barrier 2/2]

    // ---- GEMM2 (swapped): D[q][m] = mfma(h1frag, h0frag) ----
    // wave w: m-tile (w>>1), q-tiles {2*(w&1), 2*(w&1)+1}
    const int mrow = (wave >> 1) * 16 + l15;    // h0 row (= out row)
    bf16x8 hb[4];
#pragma unroll
    for (int ks = 0; ks < 4; ++ks) {
        const int ct = ks * 2 + (lhi >> 1);
        const int s  = (lhi & 1) ^ ((mrow >> 2) & 1);
        hb[ks] = *(const bf16x8*)(ldsb + 32768 + ct * 4096 + mrow * 32 + s * 16);
    }
    float* outn = out + (size_t)n * 4096;
#pragma unroll
    for (int q = 0; q < 2; ++q) {
        const int qt = (wave & 1) * 2 + q;
        const int qrow = 64 + qt * 16 + l15;    // h1 row (= out col base)
        f32x4 acc = {0.f, 0.f, 0.f, 0.f};
#pragma unroll
        for (int ks = 0; ks < 4; ++ks) {
            const int ct = ks * 2 + (lhi >> 1);
            const int s  = (lhi & 1) ^ ((qrow >> 2) & 1);
            bf16x8 ha = *(const bf16x8*)(ldsb + 32768 + ct * 4096 + qrow * 32 + s * 16);
            acc = __builtin_amdgcn_mfma_f32_16x16x32_bf16(ha, hb[ks], acc, 0, 0, 0);
        }
        __builtin_nontemporal_store(acc, (f32x4*)(outn + mrow * 64 + qt * 16 + lhi * 4));
    }
}

extern "C" void kernel_launch(void* const* d_in, const int* in_sizes, int n_in,
                              void* d_out, int out_size, void* d_ws, size_t ws_size,
                              hipStream_t stream) {
    const float* x   = (const float*)d_in[0];   // node_features [4096,2,64,128]
    const int*   deg = (const int*)d_in[1];     // [4096]
    const float* W_r = (const float*)d_in[2];   // [2,128,128]
    const float* b_r = (const float*)d_in[3];   // [2,128]
    const float* W0  = (const float*)d_in[4];   // [128,128]
    const float* b0  = (const float*)d_in[5];   // [128]
    float* out = (float*)d_out;                 // [4096,64,64]

    unsigned short* wfrag = (unsigned short*)d_ws;                    // 1 MB
    float* call = (float*)((unsigned short*)d_ws + 32 * 8 * 4 * 64 * 8); // +16 KB

    build_weights<<<256, 256, 0, stream>>>(W_r, b_r, W0, b0, wfrag, call);
    edge_kernel<<<4096, 512, 0, stream>>>(x, deg, wfrag, call, out);
}